// Round 2
// baseline (280.759 us; speedup 1.0000x reference)
//
#include <hip/hip_runtime.h>
#include <hip/hip_bf16.h>

// EdgeNetwork: per-edge MLP  out[e] = MLP(concat(x[s[e]], x[t[e]]))
// Layers: [256->128 LN tanh] [128->128 LN tanh] [128->128 LN tanh] [128->1]
// Strategy: bf16 MFMA (16x16x32), fp32 accum + fp32 LN/tanh.
// Block = 256 thr (4 waves), 128 edges/block; wave owns 32 edges (2 M-tiles).
// Weights staged to LDS transposed+swizzled in K=64 slabs, double-buffered.
//
// R2 fix: h tile is 128 rows (one per edge in block) x 128 cols x bf16 =
// 32 KB, not 16 KB. R1 overflowed the 48 KB shared array for waves 2-3
// (rowl up to 127 -> writes past end), corrupting half the hidden state.
// LDS now 64 KB total -> 2 blocks/CU.

typedef float f32x4 __attribute__((ext_vector_type(4)));
typedef __bf16 bf16x8 __attribute__((ext_vector_type(8)));

#define MFMA16(a, b, c) __builtin_amdgcn_mfma_f32_16x16x32_bf16((a), (b), (c), 0, 0, 0)

static __device__ __forceinline__ unsigned short bf16bits(float f) {
  __bf16 h = (__bf16)f;
  return __builtin_bit_cast(unsigned short, h);
}

static __device__ __forceinline__ float tanh_fast(float t) {
  // tanh(t) = 1 - 2/(e^{2t}+1); exp->inf and ->0 limits give +-1 exactly.
  float ex = __expf(2.0f * t);
  return 1.0f - 2.0f * __builtin_amdgcn_rcpf(ex + 1.0f);
}

// LDS map (65536 B total):
//   [0,16384)     weight slab buf0: Wt[col 0..127][k 0..63] bf16, byte^=(col&7)<<4
//   [16384,32768) weight slab buf1
//   [32768,65536) h tile [row 0..127][col 0..127] bf16,      byte^=(row&7)<<4
#define H_BASE 32768
__global__ __launch_bounds__(256, 2) void edge_mlp(
    const float* __restrict__ x, const int* __restrict__ ei,
    const float* __restrict__ W0, const float* __restrict__ B0,
    const float* __restrict__ W1, const float* __restrict__ B1,
    const float* __restrict__ W2, const float* __restrict__ B2,
    const float* __restrict__ W3, const float* __restrict__ B3,
    const float* __restrict__ G0, const float* __restrict__ Q0,
    const float* __restrict__ G1, const float* __restrict__ Q1,
    const float* __restrict__ G2, const float* __restrict__ Q2,
    float* __restrict__ out, int nE)
{
  __shared__ __align__(16) char lds[65536];
  const int tid  = threadIdx.x;
  const int lane = tid & 63;
  const int wv   = tid >> 6;   // wave 0..3
  const int row  = lane & 15;  // fragment row (A/C) == col lane (B)
  const int kgrp = lane >> 4;  // 0..3 k-group

  const int wbase = blockIdx.x * 128 + wv * 32;

  // Gather pointers for this wave's 32 edges (2 M-tiles of 16). Clamp tail.
  const int e0 = wbase + row;
  const int e1 = wbase + 16 + row;
  const int ec0 = e0 < nE ? e0 : nE - 1;
  const int ec1 = e1 < nE ? e1 : nE - 1;
  const float* xs0 = x + (size_t)ei[ec0] * 128;
  const float* xe0 = x + (size_t)ei[nE + ec0] * 128;
  const float* xs1 = x + (size_t)ei[ec1] * 128;
  const float* xe1 = x + (size_t)ei[nE + ec1] * 128;

  // Stage one K=64 slab of W[k][col] (row-major f32) into LDS as
  // transposed bf16 Wt[col][k], swizzled. All 256 threads participate.
  auto stage = [&](const float* Wsrc, int buf) {
    const int col = tid & 127;
    const int kb  = (tid >> 7) << 1;  // 0 or 2
    char* base = lds + buf * 16384;
    #pragma unroll
    for (int i = 0; i < 16; ++i) {
      const int k = kb + (i << 2);
      const float wa = Wsrc[k * 128 + col];
      const float wb = Wsrc[(k + 1) * 128 + col];
      const unsigned pk = (unsigned)bf16bits(wa) | ((unsigned)bf16bits(wb) << 16);
      const int off = ((col * 64 + k) * 2) ^ ((col & 7) << 4);
      *(unsigned*)(base + off) = pk;
    }
  };

  auto loadB = [&](int buf, int n, int kl) -> bf16x8 {
    const int col = n * 16 + row;
    const int off = ((col * 64 + kl) * 2) ^ ((col & 7) << 4);
    return *(const bf16x8*)(lds + buf * 16384 + off);
  };

  // Layer-0 A fragment straight from global x (concat of the two node rows).
  auto loadAg = [&](const float* xs, const float* xe, int kg) -> bf16x8 {
    const float* src = (kg < 128) ? (xs + kg) : (xe + (kg - 128));
    const float4 ua = *(const float4*)(src);
    const float4 ub = *(const float4*)(src + 4);
    bf16x8 a;
    a[0] = (__bf16)ua.x; a[1] = (__bf16)ua.y; a[2] = (__bf16)ua.z; a[3] = (__bf16)ua.w;
    a[4] = (__bf16)ub.x; a[5] = (__bf16)ub.y; a[6] = (__bf16)ub.z; a[7] = (__bf16)ub.w;
    return a;
  };

  auto loadAl = [&](int rowl, int kg) -> bf16x8 {
    const int off = ((rowl * 128 + kg) * 2) ^ ((rowl & 7) << 4);
    return *(const bf16x8*)(lds + H_BASE + off);
  };

  f32x4 acc0[8], acc1[8];
  const f32x4 z4 = {0.f, 0.f, 0.f, 0.f};

  float bc[8], gc[8], qc[8];
  #pragma unroll
  for (int n = 0; n < 8; ++n) {
    const int c = n * 16 + row;
    bc[n] = B0[c]; gc[n] = G0[c]; qc[n] = Q0[c];
  }
  #pragma unroll
  for (int n = 0; n < 8; ++n) { acc0[n] = z4; acc1[n] = z4; }

  // ---- layer 0: K=256 (4 slabs), A gathered from x ----
  for (int s = 0; s < 4; ++s) {
    stage(W0 + s * 64 * 128, s & 1);
    __syncthreads();
    #pragma unroll
    for (int kk2 = 0; kk2 < 2; ++kk2) {
      const int kl = kk2 * 32 + kgrp * 8;
      const int kg = s * 64 + kl;
      const bf16x8 a0 = loadAg(xs0, xe0, kg);
      const bf16x8 a1 = loadAg(xs1, xe1, kg);
      #pragma unroll
      for (int n = 0; n < 8; ++n) {
        const bf16x8 b = loadB(s & 1, n, kl);
        acc0[n] = MFMA16(a0, b, acc0[n]);
        acc1[n] = MFMA16(a1, b, acc1[n]);
      }
    }
  }

  // LN (+bias, gamma, beta) + tanh, write bf16 h tile (wave-private rows).
  auto ln_store = [&](f32x4* acc, int rowbase) {
    float s1[4] = {0.f, 0.f, 0.f, 0.f};
    float s2[4] = {0.f, 0.f, 0.f, 0.f};
    #pragma unroll
    for (int n = 0; n < 8; ++n)
      #pragma unroll
      for (int r = 0; r < 4; ++r) {
        const float t = acc[n][r] + bc[n];
        acc[n][r] = t;
        s1[r] += t;
        s2[r] += t * t;
      }
    #pragma unroll
    for (int off = 1; off < 16; off <<= 1)
      #pragma unroll
      for (int r = 0; r < 4; ++r) {
        s1[r] += __shfl_xor(s1[r], off);
        s2[r] += __shfl_xor(s2[r], off);
      }
    #pragma unroll
    for (int r = 0; r < 4; ++r) {
      const float mu  = s1[r] * 0.0078125f;
      const float var = s2[r] * 0.0078125f - mu * mu;
      s1[r] = mu;
      s2[r] = rsqrtf(var + 1e-5f);
    }
    #pragma unroll
    for (int n = 0; n < 8; ++n) {
      const int col = n * 16 + row;
      #pragma unroll
      for (int r = 0; r < 4; ++r) {
        const float t  = (acc[n][r] - s1[r]) * s2[r] * gc[n] + qc[n];
        const float th = tanh_fast(t);
        const int rowl = rowbase + kgrp * 4 + r;
        const int off  = ((rowl * 128 + col) * 2) ^ ((rowl & 7) << 4);
        *(unsigned short*)(lds + H_BASE + off) = bf16bits(th);
      }
    }
  };

  stage(W1, 0);               // prefetch next layer's first slab under LN
  ln_store(acc0, wv * 32);
  ln_store(acc1, wv * 32 + 16);
  __syncthreads();

  // GEMM step for layers 1/2: A from LDS h tile.
  auto cstep = [&](int buf, int s) {
    #pragma unroll
    for (int kk2 = 0; kk2 < 2; ++kk2) {
      const int kl = kk2 * 32 + kgrp * 8;
      const int kg = s * 64 + kl;
      const bf16x8 a0 = loadAl(wv * 32 + row, kg);
      const bf16x8 a1 = loadAl(wv * 32 + 16 + row, kg);
      #pragma unroll
      for (int n = 0; n < 8; ++n) {
        const bf16x8 b = loadB(buf, n, kl);
        acc0[n] = MFMA16(a0, b, acc0[n]);
        acc1[n] = MFMA16(a1, b, acc1[n]);
      }
    }
  };

  // ---- layer 1 ----
  #pragma unroll
  for (int n = 0; n < 8; ++n) {
    const int c = n * 16 + row;
    bc[n] = B1[c]; gc[n] = G1[c]; qc[n] = Q1[c];
  }
  #pragma unroll
  for (int n = 0; n < 8; ++n) { acc0[n] = z4; acc1[n] = z4; }

  cstep(0, 0);
  stage(W1 + 64 * 128, 1);
  __syncthreads();
  cstep(1, 1);

  stage(W2, 0);
  ln_store(acc0, wv * 32);
  ln_store(acc1, wv * 32 + 16);
  __syncthreads();

  // ---- layer 2 ----
  #pragma unroll
  for (int n = 0; n < 8; ++n) {
    const int c = n * 16 + row;
    bc[n] = B2[c]; gc[n] = G2[c]; qc[n] = Q2[c];
  }
  #pragma unroll
  for (int n = 0; n < 8; ++n) { acc0[n] = z4; acc1[n] = z4; }

  cstep(0, 0);
  stage(W2 + 64 * 128, 1);
  __syncthreads();
  cstep(1, 1);

  // ---- final: LN + tanh + dot W3 + b3, fully in registers ----
  float w3c[8];
  #pragma unroll
  for (int n = 0; n < 8; ++n) w3c[n] = W3[n * 16 + row];
  const float b3v = B3[0];

  auto ln_dot = [&](f32x4* acc, int ebase) {
    float s1[4] = {0.f, 0.f, 0.f, 0.f};
    float s2[4] = {0.f, 0.f, 0.f, 0.f};
    #pragma unroll
    for (int n = 0; n < 8; ++n)
      #pragma unroll
      for (int r = 0; r < 4; ++r) {
        const float t = acc[n][r] + bc[n];
        acc[n][r] = t;
        s1[r] += t;
        s2[r] += t * t;
      }
    #pragma unroll
    for (int off = 1; off < 16; off <<= 1)
      #pragma unroll
      for (int r = 0; r < 4; ++r) {
        s1[r] += __shfl_xor(s1[r], off);
        s2[r] += __shfl_xor(s2[r], off);
      }
    float d[4];
    #pragma unroll
    for (int r = 0; r < 4; ++r) {
      const float mu  = s1[r] * 0.0078125f;
      const float var = s2[r] * 0.0078125f - mu * mu;
      s1[r] = mu;
      s2[r] = rsqrtf(var + 1e-5f);
      d[r] = 0.f;
    }
    #pragma unroll
    for (int n = 0; n < 8; ++n)
      #pragma unroll
      for (int r = 0; r < 4; ++r) {
        const float t = (acc[n][r] - s1[r]) * s2[r] * gc[n] + qc[n];
        d[r] += tanh_fast(t) * w3c[n];
      }
    #pragma unroll
    for (int off = 1; off < 16; off <<= 1)
      #pragma unroll
      for (int r = 0; r < 4; ++r)
        d[r] += __shfl_xor(d[r], off);
    #pragma unroll
    for (int r = 0; r < 4; ++r) {
      const int e = ebase + kgrp * 4 + r;
      if (row == r && e < nE) out[e] = d[r] + b3v;
    }
  };

  ln_dot(acc0, wbase);
  ln_dot(acc1, wbase + 16);
}

extern "C" void kernel_launch(void* const* d_in, const int* in_sizes, int n_in,
                              void* d_out, int out_size, void* d_ws, size_t ws_size,
                              hipStream_t stream) {
  const float* x  = (const float*)d_in[0];
  const int*   ei = (const int*)d_in[1];
  const float* W0 = (const float*)d_in[2];
  const float* B0 = (const float*)d_in[3];
  const float* W1 = (const float*)d_in[4];
  const float* B1 = (const float*)d_in[5];
  const float* W2 = (const float*)d_in[6];
  const float* B2 = (const float*)d_in[7];
  const float* W3 = (const float*)d_in[8];
  const float* B3 = (const float*)d_in[9];
  const float* G0 = (const float*)d_in[10];
  const float* Q0 = (const float*)d_in[11];
  const float* G1 = (const float*)d_in[12];
  const float* Q1 = (const float*)d_in[13];
  const float* G2 = (const float*)d_in[14];
  const float* Q2 = (const float*)d_in[15];
  float* out = (float*)d_out;

  const int nE = in_sizes[1] / 2;
  const int blocks = (nE + 127) / 128;
  hipLaunchKernelGGL(edge_mlp, dim3(blocks), dim3(256), 0, stream,
                     x, ei, W0, B0, W1, B1, W2, B2, W3, B3,
                     G0, Q0, G1, Q1, G2, Q2, out, nE);
}

// Round 3
// 247.949 us; speedup vs baseline: 1.1323x; 1.1323x over previous
//
#include <hip/hip_runtime.h>
#include <hip/hip_bf16.h>

// EdgeNetwork: per-edge MLP  out[e] = MLP(concat(x[s[e]], x[t[e]]))
// Layers: [256->128 LN tanh] [128->128 LN tanh] [128->128 LN tanh] [128->1]
// bf16 MFMA 16x16x32, fp32 accum + fp32 LN/tanh.
// Block = 256 thr (4 waves), 128 edges/block; wave owns 32 edges (2 M-tiles).
//
// R3: (a) weights pre-converted ONCE by prep kernel into d_ws as the exact
// swizzled bf16 LDS image; main kernel stages via global_load_lds width=16
// (no VALU cvt, no ds_write bank conflicts). (b) layer-0 A gather hoisted
// into bf16 registers before the first barrier. (c) stage(s+1) issued
// before mfma(s) so load latency hides under MFMA.

typedef float f32x4 __attribute__((ext_vector_type(4)));
typedef __bf16 bf16x8 __attribute__((ext_vector_type(8)));

#define MFMA16(a, b, c) __builtin_amdgcn_mfma_f32_16x16x32_bf16((a), (b), (c), 0, 0, 0)

static __device__ __forceinline__ unsigned short bf16bits(float f) {
  __bf16 h = (__bf16)f;
  return __builtin_bit_cast(unsigned short, h);
}

static __device__ __forceinline__ float tanh_fast(float t) {
  float ex = __expf(2.0f * t);
  return 1.0f - 2.0f * __builtin_amdgcn_rcpf(ex + 1.0f);
}

static __device__ __forceinline__ void gload_lds16(const void* g, void* l) {
  __builtin_amdgcn_global_load_lds(
      (const __attribute__((address_space(1))) void*)g,
      (__attribute__((address_space(3))) void*)l, 16, 0, 0);
}

// Build swizzled bf16 weight image: slab t in [0,8) -> 16384 B at ws+t*16384.
// t 0..3 = W0 (K=256), t 4..5 = W1, t 6..7 = W2. Within a slab:
// byte ((col*64+k)*2)^((col&7)<<4) holds Wt[col][k] (bf16), k in [0,64).
__global__ void prep_weights(const float* __restrict__ W0,
                             const float* __restrict__ W1,
                             const float* __restrict__ W2,
                             char* __restrict__ ws) {
  const int t = blockIdx.x;
  const float* src = (t < 4) ? (W0 + t * 8192)
                   : (t < 6) ? (W1 + (t - 4) * 8192)
                             : (W2 + (t - 6) * 8192);
  char* base = ws + t * 16384;
  const int tid = threadIdx.x;
  const int col = tid & 127;
  const int kb  = (tid >> 7) << 1;
  #pragma unroll
  for (int i = 0; i < 16; ++i) {
    const int k = kb + (i << 2);
    const float wa = src[k * 128 + col];
    const float wb = src[(k + 1) * 128 + col];
    const unsigned pk = (unsigned)bf16bits(wa) | ((unsigned)bf16bits(wb) << 16);
    const int off = ((col * 64 + k) * 2) ^ ((col & 7) << 4);
    *(unsigned*)(base + off) = pk;
  }
}

// LDS map (65536 B):
//   [0,16384)     weight slab buf0 (swizzled image)
//   [16384,32768) weight slab buf1
//   [32768,65536) h tile [row 0..127][col 0..127] bf16, byte^=(row&7)<<4
#define H_BASE 32768
__global__ __launch_bounds__(256, 2) void edge_mlp(
    const float* __restrict__ x, const int* __restrict__ ei,
    const float* __restrict__ W0, const float* __restrict__ B0,
    const float* __restrict__ W1, const float* __restrict__ B1,
    const float* __restrict__ W2, const float* __restrict__ B2,
    const float* __restrict__ W3, const float* __restrict__ B3,
    const float* __restrict__ G0, const float* __restrict__ Q0,
    const float* __restrict__ G1, const float* __restrict__ Q1,
    const float* __restrict__ G2, const float* __restrict__ Q2,
    const char* __restrict__ ws, int use_ws,
    float* __restrict__ out, int nE)
{
  __shared__ __align__(16) char lds[65536];
  const int tid  = threadIdx.x;
  const int lane = tid & 63;
  const int wv   = tid >> 6;
  const int row  = lane & 15;
  const int kgrp = lane >> 4;

  const int wbase = blockIdx.x * 128 + wv * 32;

  const int e0 = wbase + row;
  const int e1 = wbase + 16 + row;
  const int ec0 = e0 < nE ? e0 : nE - 1;
  const int ec1 = e1 < nE ? e1 : nE - 1;
  const float* xs0 = x + (size_t)ei[ec0] * 128;
  const float* xe0 = x + (size_t)ei[nE + ec0] * 128;
  const float* xs1 = x + (size_t)ei[ec1] * 128;
  const float* xe1 = x + (size_t)ei[nE + ec1] * 128;

  // ---- stage: ws image -> LDS via global_load_lds (4 x 1KB per wave) ----
  auto stageW = [&](int t, int buf) {
    #pragma unroll
    for (int c = 0; c < 4; ++c) {
      const int o = wv * 4096 + c * 1024;
      gload_lds16(ws + t * 16384 + o + lane * 16, lds + buf * 16384 + o);
    }
  };
  // Fallback (ws too small): R2-style in-kernel convert.
  auto stageOld = [&](int t, int buf) {
    const float* src = (t < 4) ? (W0 + t * 8192)
                     : (t < 6) ? (W1 + (t - 4) * 8192)
                               : (W2 + (t - 6) * 8192);
    const int col = tid & 127;
    const int kb  = (tid >> 7) << 1;
    char* base = lds + buf * 16384;
    #pragma unroll
    for (int i = 0; i < 16; ++i) {
      const int k = kb + (i << 2);
      const float wa = src[k * 128 + col];
      const float wb = src[(k + 1) * 128 + col];
      const unsigned pk = (unsigned)bf16bits(wa) | ((unsigned)bf16bits(wb) << 16);
      const int off = ((col * 64 + k) * 2) ^ ((col & 7) << 4);
      *(unsigned*)(base + off) = pk;
    }
  };
  auto stage = [&](int t, int buf) {
    if (use_ws) stageW(t, buf); else stageOld(t, buf);
  };

  auto loadB = [&](int buf, int n, int kl) -> bf16x8 {
    const int col = n * 16 + row;
    const int off = ((col * 64 + kl) * 2) ^ ((col & 7) << 4);
    return *(const bf16x8*)(lds + buf * 16384 + off);
  };

  auto loadAg = [&](const float* xs, const float* xe, int kg) -> bf16x8 {
    const float* src = (kg < 128) ? (xs + kg) : (xe + (kg - 128));
    const float4 ua = *(const float4*)(src);
    const float4 ub = *(const float4*)(src + 4);
    bf16x8 a;
    a[0] = (__bf16)ua.x; a[1] = (__bf16)ua.y; a[2] = (__bf16)ua.z; a[3] = (__bf16)ua.w;
    a[4] = (__bf16)ub.x; a[5] = (__bf16)ub.y; a[6] = (__bf16)ub.z; a[7] = (__bf16)ub.w;
    return a;
  };

  auto loadAl = [&](int rowl, int kg) -> bf16x8 {
    const int off = ((rowl * 128 + kg) * 2) ^ ((rowl & 7) << 4);
    return *(const bf16x8*)(lds + H_BASE + off);
  };

  // ---- hoist the whole layer-0 gather into bf16 registers ----
  bf16x8 af0[8], af1[8];  // index u = s*2+kk2, k base = u*32 + kgrp*8
  #pragma unroll
  for (int u = 0; u < 8; ++u) {
    const int kg = u * 32 + kgrp * 8;
    af0[u] = loadAg(xs0, xe0, kg);
    af1[u] = loadAg(xs1, xe1, kg);
  }

  f32x4 acc0[8], acc1[8];
  const f32x4 z4 = {0.f, 0.f, 0.f, 0.f};
  float bc[8], gc[8], qc[8];
  #pragma unroll
  for (int n = 0; n < 8; ++n) {
    const int c = n * 16 + row;
    bc[n] = B0[c]; gc[n] = G0[c]; qc[n] = Q0[c];
  }
  #pragma unroll
  for (int n = 0; n < 8; ++n) { acc0[n] = z4; acc1[n] = z4; }

  auto mfmaL0 = [&](int s, int buf) {
    #pragma unroll
    for (int kk2 = 0; kk2 < 2; ++kk2) {
      const int kl = kk2 * 32 + kgrp * 8;
      const bf16x8 a0 = af0[s * 2 + kk2];
      const bf16x8 a1 = af1[s * 2 + kk2];
      #pragma unroll
      for (int n = 0; n < 8; ++n) {
        const bf16x8 b = loadB(buf, n, kl);
        acc0[n] = MFMA16(a0, b, acc0[n]);
        acc1[n] = MFMA16(a1, b, acc1[n]);
      }
    }
  };

  auto cstep = [&](int buf, int s) {
    #pragma unroll
    for (int kk2 = 0; kk2 < 2; ++kk2) {
      const int kl = kk2 * 32 + kgrp * 8;
      const int kg = s * 64 + kl;
      const bf16x8 a0 = loadAl(wv * 32 + row, kg);
      const bf16x8 a1 = loadAl(wv * 32 + 16 + row, kg);
      #pragma unroll
      for (int n = 0; n < 8; ++n) {
        const bf16x8 b = loadB(buf, n, kl);
        acc0[n] = MFMA16(a0, b, acc0[n]);
        acc1[n] = MFMA16(a1, b, acc1[n]);
      }
    }
  };

  auto ln_store = [&](f32x4* acc, int rowbase) {
    float s1[4] = {0.f, 0.f, 0.f, 0.f};
    float s2[4] = {0.f, 0.f, 0.f, 0.f};
    #pragma unroll
    for (int n = 0; n < 8; ++n)
      #pragma unroll
      for (int r = 0; r < 4; ++r) {
        const float t = acc[n][r] + bc[n];
        acc[n][r] = t;
        s1[r] += t;
        s2[r] += t * t;
      }
    #pragma unroll
    for (int off = 1; off < 16; off <<= 1)
      #pragma unroll
      for (int r = 0; r < 4; ++r) {
        s1[r] += __shfl_xor(s1[r], off);
        s2[r] += __shfl_xor(s2[r], off);
      }
    #pragma unroll
    for (int r = 0; r < 4; ++r) {
      const float mu  = s1[r] * 0.0078125f;
      const float var = s2[r] * 0.0078125f - mu * mu;
      s1[r] = mu;
      s2[r] = __builtin_amdgcn_rsqf(var + 1e-5f);
    }
    #pragma unroll
    for (int n = 0; n < 8; ++n) {
      const int col = n * 16 + row;
      #pragma unroll
      for (int r = 0; r < 4; ++r) {
        const float t  = (acc[n][r] - s1[r]) * s2[r] * gc[n] + qc[n];
        const float th = tanh_fast(t);
        const int rowl = rowbase + kgrp * 4 + r;
        const int off  = ((rowl * 128 + col) * 2) ^ ((rowl & 7) << 4);
        *(unsigned short*)(lds + H_BASE + off) = bf16bits(th);
      }
    }
  };

  // ---------------- schedule ----------------
  stage(0, 0); __syncthreads();                       // W0 s0
  stage(1, 1); mfmaL0(0, 0); __syncthreads();         // W0 s1 under mfma
  stage(2, 0); mfmaL0(1, 1); __syncthreads();
  stage(3, 1); mfmaL0(2, 0); __syncthreads();
  stage(4, 0); mfmaL0(3, 1);                          // W1 s0 prefetch

  #pragma unroll
  for (int n = 0; n < 8; ++n) {
    const int c = n * 16 + row;
    // save layer-1 params; LN uses current bc/gc/qc (layer 0)
  }
  ln_store(acc0, wv * 32);
  ln_store(acc1, wv * 32 + 16);
  __syncthreads();

  // ---- layer 1 ----
  #pragma unroll
  for (int n = 0; n < 8; ++n) {
    const int c = n * 16 + row;
    bc[n] = B1[c]; gc[n] = G1[c]; qc[n] = Q1[c];
  }
  #pragma unroll
  for (int n = 0; n < 8; ++n) { acc0[n] = z4; acc1[n] = z4; }

  stage(5, 1); cstep(0, 0);                           // W1 s1 under cstep
  __syncthreads();
  stage(6, 0); cstep(1, 1);                           // W2 s0 under cstep
  ln_store(acc0, wv * 32);
  // note: ln_store consumed acc0 with layer-1 params -- set below BEFORE use
  ln_store(acc1, wv * 32 + 16);
  __syncthreads();

  // ---- layer 2 ----
  #pragma unroll
  for (int n = 0; n < 8; ++n) {
    const int c = n * 16 + row;
    bc[n] = B2[c]; gc[n] = G2[c]; qc[n] = Q2[c];
  }
  #pragma unroll
  for (int n = 0; n < 8; ++n) { acc0[n] = z4; acc1[n] = z4; }

  stage(7, 1); cstep(0, 0);                           // W2 s1 under cstep
  __syncthreads();
  cstep(1, 1);

  // ---- final: LN + tanh + dot W3 + b3 ----
  float w3c[8];
  #pragma unroll
  for (int n = 0; n < 8; ++n) w3c[n] = W3[n * 16 + row];
  const float b3v = B3[0];

  auto ln_dot = [&](f32x4* acc, int ebase) {
    float s1[4] = {0.f, 0.f, 0.f, 0.f};
    float s2[4] = {0.f, 0.f, 0.f, 0.f};
    #pragma unroll
    for (int n = 0; n < 8; ++n)
      #pragma unroll
      for (int r = 0; r < 4; ++r) {
        const float t = acc[n][r] + bc[n];
        acc[n][r] = t;
        s1[r] += t;
        s2[r] += t * t;
      }
    #pragma unroll
    for (int off = 1; off < 16; off <<= 1)
      #pragma unroll
      for (int r = 0; r < 4; ++r) {
        s1[r] += __shfl_xor(s1[r], off);
        s2[r] += __shfl_xor(s2[r], off);
      }
    float d[4];
    #pragma unroll
    for (int r = 0; r < 4; ++r) {
      const float mu  = s1[r] * 0.0078125f;
      const float var = s2[r] * 0.0078125f - mu * mu;
      s1[r] = mu;
      s2[r] = __builtin_amdgcn_rsqf(var + 1e-5f);
      d[r] = 0.f;
    }
    #pragma unroll
    for (int n = 0; n < 8; ++n)
      #pragma unroll
      for (int r = 0; r < 4; ++r) {
        const float t = (acc[n][r] - s1[r]) * s2[r] * gc[n] + qc[n];
        d[r] += tanh_fast(t) * w3c[n];
      }
    #pragma unroll
    for (int off = 1; off < 16; off <<= 1)
      #pragma unroll
      for (int r = 0; r < 4; ++r)
        d[r] += __shfl_xor(d[r], off);
    #pragma unroll
    for (int r = 0; r < 4; ++r) {
      const int e = ebase + kgrp * 4 + r;
      if (row == r && e < nE) out[e] = d[r] + b3v;
    }
  };

  ln_dot(acc0, wbase);
  ln_dot(acc1, wbase + 16);
}

extern "C" void kernel_launch(void* const* d_in, const int* in_sizes, int n_in,
                              void* d_out, int out_size, void* d_ws, size_t ws_size,
                              hipStream_t stream) {
  const float* x  = (const float*)d_in[0];
  const int*   ei = (const int*)d_in[1];
  const float* W0 = (const float*)d_in[2];
  const float* B0 = (const float*)d_in[3];
  const float* W1 = (const float*)d_in[4];
  const float* B1 = (const float*)d_in[5];
  const float* W2 = (const float*)d_in[6];
  const float* B2 = (const float*)d_in[7];
  const float* W3 = (const float*)d_in[8];
  const float* B3 = (const float*)d_in[9];
  const float* G0 = (const float*)d_in[10];
  const float* Q0 = (const float*)d_in[11];
  const float* G1 = (const float*)d_in[12];
  const float* Q1 = (const float*)d_in[13];
  const float* G2 = (const float*)d_in[14];
  const float* Q2 = (const float*)d_in[15];
  float* out = (float*)d_out;

  const int nE = in_sizes[1] / 2;
  const int blocks = (nE + 127) / 128;
  const int use_ws = (ws_size >= 131072) ? 1 : 0;

  if (use_ws)
    hipLaunchKernelGGL(prep_weights, dim3(8), dim3(256), 0, stream, W0, W1, W2, (char*)d_ws);

  hipLaunchKernelGGL(edge_mlp, dim3(blocks), dim3(256), 0, stream,
                     x, ei, W0, B0, W1, B1, W2, B2, W3, B3,
                     G0, Q0, G1, Q1, G2, Q2,
                     (const char*)d_ws, use_ws, out, nE);
}